// Round 10
// baseline (827.180 us; speedup 1.0000x reference)
//
#include <hip/hip_runtime.h>
#include <hip/hip_cooperative_groups.h>
#include <math.h>

namespace cg = cooperative_groups;

#define N_NODES 50000
#define N_EDGES 800000
#define HD 256          // NHEAD * OUT_DIM
#define OUT_DIM 64
#define NHEAD 4
#define SLOPE 0.2f
#define BN_EPS 1e-5f
#define LOG2E 1.4426950408889634f

typedef __attribute__((ext_vector_type(8))) short short8;
typedef __attribute__((ext_vector_type(4))) float float4v;

__device__ __forceinline__ float leaky(float x) { return x >= 0.f ? x : SLOPE * x; }

__device__ __forceinline__ float bf2f(unsigned short u) {
    return __uint_as_float(((unsigned)u) << 16);
}
__device__ __forceinline__ unsigned short f2bf(float f) {
    unsigned u = __float_as_uint(f);
    unsigned r = (u + 0x7fffu + ((u >> 16) & 1u)) >> 16;
    return (unsigned short)r;
}

// ---------------------------------------------------------------------------
// Cooperative prep + CSR build: one dispatch replaces prep/hist/scan1/scan2/
// scatter. Phases separated by grid.sync():
//  0: feat cast, W transposes (coalesced reads), zero cnt/cursor/sums
//  1: histogram   2: 196 chunk scans   3: block-0 scans chunk sums
//  4: finalize offs (+ offs[N]=E)      5: scatter src ids into CSR order
// ---------------------------------------------------------------------------
__global__ __launch_bounds__(256) void prep_csr_kernel(const float* __restrict__ feat,
                                                       const float* __restrict__ W_src,
                                                       const float* __restrict__ W_dst,
                                                       const float* __restrict__ fc_W,
                                                       const int* __restrict__ src,
                                                       const int* __restrict__ dst,
                                                       unsigned short* __restrict__ feat_bf,
                                                       unsigned short* __restrict__ WtS,
                                                       unsigned short* __restrict__ WtD,
                                                       unsigned short* __restrict__ WtF,
                                                       int* __restrict__ cnt2,
                                                       float* __restrict__ sums,
                                                       int* __restrict__ offs,
                                                       int* __restrict__ bsum,
                                                       int* __restrict__ bpre,
                                                       int* __restrict__ srcl) {
    cg::grid_group grid = cg::this_grid();
    const int t = threadIdx.x;
    const int tid = blockIdx.x * 256 + t;
    const int nthr = gridDim.x * 256;
    int* cnt = cnt2;
    int* cursor = cnt2 + N_NODES;

    // phase 0
    for (int i = tid; i < (N_NODES * 256) / 4; i += nthr) {
        const float4 v = ((const float4*)feat)[i];
        ushort4 o;
        o.x = f2bf(v.x); o.y = f2bf(v.y); o.z = f2bf(v.z); o.w = f2bf(v.w);
        ((ushort4*)feat_bf)[i] = o;
    }
    for (int i = tid; i < 256 * 256; i += nthr) {      // n = i&255 (coalesced read)
        const int n = i & 255, k = i >> 8;
        WtS[(size_t)n * 256 + k] = f2bf(W_src[(size_t)k * 256 + n]);
        WtD[(size_t)n * 256 + k] = f2bf(W_dst[(size_t)k * 256 + n]);
    }
    for (int i = tid; i < 64 * 256; i += nthr) {
        const int n = i & 63, k = i >> 6;
        WtF[(size_t)n * 256 + k] = f2bf(fc_W[(size_t)k * 64 + n]);
    }
    for (int i = tid; i < 2 * N_NODES; i += nthr) cnt2[i] = 0;
    if (tid < 128) sums[tid] = 0.f;
    grid.sync();

    // phase 1: histogram
    for (int i = tid; i < N_EDGES; i += nthr) atomicAdd(&cnt[dst[i]], 1);
    grid.sync();

    // phase 2: chunk-local exclusive scans (196 chunks of 256 nodes)
    __shared__ int s[256];
    if (blockIdx.x < 196) {
        const int i = blockIdx.x * 256 + t;
        const int v = (i < N_NODES) ? cnt[i] : 0;
        s[t] = v;
        __syncthreads();
        for (int o = 1; o < 256; o <<= 1) {
            const int x = (t >= o) ? s[t - o] : 0;
            __syncthreads();
            s[t] += x;
            __syncthreads();
        }
        if (i < N_NODES) offs[i] = s[t] - v;
        if (t == 255) bsum[blockIdx.x] = s[255];
    }
    grid.sync();

    // phase 3: block 0 scans the 196 chunk sums
    if (blockIdx.x == 0) {
        const int v = (t < 196) ? bsum[t] : 0;
        s[t] = v;
        __syncthreads();
        for (int o = 1; o < 256; o <<= 1) {
            const int x = (t >= o) ? s[t - o] : 0;
            __syncthreads();
            s[t] += x;
            __syncthreads();
        }
        bpre[t] = s[t] - v;
    }
    grid.sync();

    // phase 4: finalize offs
    for (int i = tid; i < N_NODES; i += nthr) offs[i] += bpre[i >> 8];
    if (tid == 0) offs[N_NODES] = N_EDGES;
    grid.sync();

    // phase 5: scatter
    for (int i = tid; i < N_EDGES; i += nthr) {
        const int d = dst[i];
        const int p = offs[d] + atomicAdd(&cursor[d], 1);
        srcl[p] = src[i];
    }
}

// ---------------------------------------------------------------------------
// Dual-output bf16 MFMA GEMM, fragment-ordered LDS (64 KB for both B chunks).
// Grid (391, 4): 128 rows x 64 cols of BOTH outputs. Each fragment is one
// conflict-free ds_read_b128. A: 16 fragments prefetched to registers.
// ---------------------------------------------------------------------------
__global__ __launch_bounds__(256) void proj_kernel(const unsigned short* __restrict__ A,
                                                   const unsigned short* __restrict__ BtS,
                                                   const unsigned short* __restrict__ BtD,
                                                   const float* __restrict__ bS,
                                                   const float* __restrict__ bD,
                                                   unsigned short* __restrict__ CS,
                                                   unsigned short* __restrict__ CD) {
    __shared__ unsigned short Bs[2][64 * 256];   // fragment-ordered, 64 KB

    const int t    = threadIdx.x;
    const int w    = t >> 6;
    const int lane = t & 63;
    const int q    = lane >> 4;
    const int l16  = lane & 15;
    const int m0   = blockIdx.x * 128;
    const int c0   = blockIdx.y * 64;

    // ---- A prefetch ----
    int ar0 = m0 + w * 32 + l16;
    int ar1 = ar0 + 16;
    if (ar0 > N_NODES - 1) ar0 = N_NODES - 1;
    if (ar1 > N_NODES - 1) ar1 = N_NODES - 1;
    const unsigned short* Ab0 = A + (size_t)ar0 * 256 + q * 8;
    const unsigned short* Ab1 = A + (size_t)ar1 * 256 + q * 8;
    short8 afr0[8], afr1[8];
#pragma unroll
    for (int kk = 0; kk < 8; ++kk) {
        afr0[kk] = *(const short8*)(Ab0 + kk * 32);
        afr1[kk] = *(const short8*)(Ab1 + kk * 32);
    }

    // ---- stage both B chunks, fragment order ----
    {
        const int r   = t >> 2;        // B row (= output col) 0..63
        const int seg = t & 3;
        const int c   = r >> 4;
        const int L   = r & 15;
        const unsigned short* gS = BtS + (size_t)(c0 + r) * 256 + seg * 64;
        const unsigned short* gD = BtD + (size_t)(c0 + r) * 256 + seg * 64;
#pragma unroll
        for (int kk2 = 0; kk2 < 2; ++kk2) {
            const int kk = seg * 2 + kk2;
#pragma unroll
            for (int q2 = 0; q2 < 4; ++q2) {
                *(short8*)(&Bs[0][((c * 8 + kk) * 64 + q2 * 16 + L) * 8]) =
                    *(const short8*)(gS + kk2 * 32 + q2 * 8);
                *(short8*)(&Bs[1][((c * 8 + kk) * 64 + q2 * 16 + L) * 8]) =
                    *(const short8*)(gD + kk2 * 32 + q2 * 8);
            }
        }
    }
    __syncthreads();

    float4v aS0[4] = {}, aS1[4] = {}, aD0[4] = {}, aD1[4] = {};

#pragma unroll
    for (int kk = 0; kk < 8; ++kk) {
        const short8 af0 = afr0[kk];
        const short8 af1 = afr1[kk];
#pragma unroll
        for (int c = 0; c < 4; ++c) {
            const short8 bs = *(const short8*)(&Bs[0][((c * 8 + kk) * 64 + lane) * 8]);
            aS0[c] = __builtin_amdgcn_mfma_f32_16x16x32_bf16(af0, bs, aS0[c], 0, 0, 0);
            aS1[c] = __builtin_amdgcn_mfma_f32_16x16x32_bf16(af1, bs, aS1[c], 0, 0, 0);
            const short8 bd = *(const short8*)(&Bs[1][((c * 8 + kk) * 64 + lane) * 8]);
            aD0[c] = __builtin_amdgcn_mfma_f32_16x16x32_bf16(af0, bd, aD0[c], 0, 0, 0);
            aD1[c] = __builtin_amdgcn_mfma_f32_16x16x32_bf16(af1, bd, aD1[c], 0, 0, 0);
        }
    }

#pragma unroll
    for (int c = 0; c < 4; ++c) {
        const int col = c0 + c * 16 + l16;
        const float vbS = bS[col];
        const float vbD = bD[col];
#pragma unroll
        for (int i = 0; i < 4; ++i) {
            const int r0 = m0 + w * 32 + q * 4 + i;
            const int r1 = r0 + 16;
            if (r0 < N_NODES) {
                CS[(size_t)r0 * 256 + col] = f2bf(aS0[c][i] + vbS);
                CD[(size_t)r0 * 256 + col] = f2bf(aD0[c][i] + vbD);
            }
            if (r1 < N_NODES) {
                CS[(size_t)r1 * 256 + col] = f2bf(aS1[c][i] + vbS);
                CD[(size_t)r1 * 256 + col] = f2bf(aD1[c][i] + vbD);
            }
        }
    }
}

// ---------------------------------------------------------------------------
// Fused GATv2 score + softmax + aggregation: one wave per node (offs final).
// ---------------------------------------------------------------------------
__global__ __launch_bounds__(256) void agg_fused_kernel(const unsigned short* __restrict__ h_src,
                                                        const unsigned short* __restrict__ h_dst,
                                                        const int* __restrict__ srcl,
                                                        const int* __restrict__ offs,
                                                        const float* __restrict__ attn,
                                                        const float* __restrict__ out_bias,
                                                        unsigned short* __restrict__ rst) {
    const int node = blockIdx.x * 4 + (threadIdx.x >> 6);
    const int lane = threadIdx.x & 63;
    const int d4 = lane * 4;

    const int beg = offs[node];
    const int end = offs[node + 1];

    const ushort4 hdv = *(const ushort4*)(h_dst + (size_t)node * 256 + d4);
    const float hd0 = bf2f(hdv.x), hd1 = bf2f(hdv.y), hd2 = bf2f(hdv.z), hd3 = bf2f(hdv.w);
    const float4 araw = *(const float4*)(attn + d4);
    const float av0 = araw.x * LOG2E, av1 = araw.y * LOG2E,
                av2 = araw.z * LOG2E, av3 = araw.w * LOG2E;
    const float aw0 = av0 * SLOPE, aw1 = av1 * SLOPE,
                aw2 = av2 * SLOPE, aw3 = av3 * SLOPE;

    float wsum = 0.f, a0 = 0.f, a1 = 0.f, a2 = 0.f, a3 = 0.f;

    int p = beg;
    for (; p + 2 <= end; p += 2) {
        const int s0 = srcl[p];
        const int s1 = srcl[p + 1];
        const ushort4 va = *(const ushort4*)(h_src + (size_t)s0 * 256 + d4);
        const ushort4 vb = *(const ushort4*)(h_src + (size_t)s1 * 256 + d4);

        const float ra0 = bf2f(va.x), ra1 = bf2f(va.y), ra2 = bf2f(va.z), ra3 = bf2f(va.w);
        const float rb0 = bf2f(vb.x), rb1 = bf2f(vb.y), rb2 = bf2f(vb.z), rb3 = bf2f(vb.w);

        const float ya0 = ra0 + hd0, ya1 = ra1 + hd1, ya2 = ra2 + hd2, ya3 = ra3 + hd3;
        const float yb0 = rb0 + hd0, yb1 = rb1 + hd1, yb2 = rb2 + hd2, yb3 = rb3 + hd3;

        float pa = av0 * fmaxf(ya0, 0.f) + aw0 * fminf(ya0, 0.f);
        pa = fmaf(av1, fmaxf(ya1, 0.f), fmaf(aw1, fminf(ya1, 0.f), pa));
        pa = fmaf(av2, fmaxf(ya2, 0.f), fmaf(aw2, fminf(ya2, 0.f), pa));
        pa = fmaf(av3, fmaxf(ya3, 0.f), fmaf(aw3, fminf(ya3, 0.f), pa));
        float pb = av0 * fmaxf(yb0, 0.f) + aw0 * fminf(yb0, 0.f);
        pb = fmaf(av1, fmaxf(yb1, 0.f), fmaf(aw1, fminf(yb1, 0.f), pb));
        pb = fmaf(av2, fmaxf(yb2, 0.f), fmaf(aw2, fminf(yb2, 0.f), pb));
        pb = fmaf(av3, fmaxf(yb3, 0.f), fmaf(aw3, fminf(yb3, 0.f), pb));

        pa += __shfl_xor(pa, 1); pb += __shfl_xor(pb, 1);
        pa += __shfl_xor(pa, 2); pb += __shfl_xor(pb, 2);
        pa += __shfl_xor(pa, 4); pb += __shfl_xor(pb, 4);
        pa += __shfl_xor(pa, 8); pb += __shfl_xor(pb, 8);

        const float wa = __builtin_amdgcn_exp2f(pa);
        const float wb = __builtin_amdgcn_exp2f(pb);
        wsum += wa + wb;
        a0 = fmaf(wa, ra0, fmaf(wb, rb0, a0));
        a1 = fmaf(wa, ra1, fmaf(wb, rb1, a1));
        a2 = fmaf(wa, ra2, fmaf(wb, rb2, a2));
        a3 = fmaf(wa, ra3, fmaf(wb, rb3, a3));
    }
    if (p < end) {
        const int s0 = srcl[p];
        const ushort4 va = *(const ushort4*)(h_src + (size_t)s0 * 256 + d4);
        const float ra0 = bf2f(va.x), ra1 = bf2f(va.y), ra2 = bf2f(va.z), ra3 = bf2f(va.w);
        const float ya0 = ra0 + hd0, ya1 = ra1 + hd1, ya2 = ra2 + hd2, ya3 = ra3 + hd3;
        float pa = av0 * fmaxf(ya0, 0.f) + aw0 * fminf(ya0, 0.f);
        pa = fmaf(av1, fmaxf(ya1, 0.f), fmaf(aw1, fminf(ya1, 0.f), pa));
        pa = fmaf(av2, fmaxf(ya2, 0.f), fmaf(aw2, fminf(ya2, 0.f), pa));
        pa = fmaf(av3, fmaxf(ya3, 0.f), fmaf(aw3, fminf(ya3, 0.f), pa));
        pa += __shfl_xor(pa, 1);
        pa += __shfl_xor(pa, 2);
        pa += __shfl_xor(pa, 4);
        pa += __shfl_xor(pa, 8);
        const float wa = __builtin_amdgcn_exp2f(pa);
        wsum += wa;
        a0 = fmaf(wa, ra0, a0);
        a1 = fmaf(wa, ra1, a1);
        a2 = fmaf(wa, ra2, a2);
        a3 = fmaf(wa, ra3, a3);
    }

    const float inv = (wsum > 0.f) ? 1.f / wsum : 0.f;
    const float4 ob = *(const float4*)(out_bias + d4);
    ushort4 o;
    o.x = f2bf(fmaf(a0, inv, ob.x));
    o.y = f2bf(fmaf(a1, inv, ob.y));
    o.z = f2bf(fmaf(a2, inv, ob.z));
    o.w = f2bf(fmaf(a3, inv, ob.w));
    *(ushort4*)(rst + (size_t)node * 256 + d4) = o;
}

// ---------------------------------------------------------------------------
// Cooperative fc GEMM + BatchNorm: MFMA + stats -> grid.sync -> normalize
// FROM REGISTERS + LeakyReLU + single z store. 391 blocks x 128 rows.
// ---------------------------------------------------------------------------
__global__ __launch_bounds__(256) void fcbn_kernel(const unsigned short* __restrict__ A,
                                                   const unsigned short* __restrict__ Bt,
                                                   const float* __restrict__ bias,
                                                   float* __restrict__ z,
                                                   float* __restrict__ sums,
                                                   const float* __restrict__ gamma,
                                                   const float* __restrict__ beta) {
    cg::grid_group grid = cg::this_grid();
    const int t    = threadIdx.x;
    const int w    = t >> 6;
    const int lane = t & 63;
    const int q    = lane >> 4;
    const int l16  = lane & 15;
    const int m0   = blockIdx.x * 128;

    __shared__ float ssum[64], ssq[64];
    if (t < 64) { ssum[t] = 0.f; ssq[t] = 0.f; }

    int ar0 = m0 + w * 32 + l16;
    int ar1 = ar0 + 16;
    if (ar0 > N_NODES - 1) ar0 = N_NODES - 1;
    if (ar1 > N_NODES - 1) ar1 = N_NODES - 1;
    const unsigned short* Ab0 = A + (size_t)ar0 * 256 + q * 8;
    const unsigned short* Ab1 = A + (size_t)ar1 * 256 + q * 8;
    const unsigned short* Btb = Bt + (size_t)l16 * 256 + q * 8;

    float4v a0[4] = {}, a1[4] = {};

    for (int k0 = 0; k0 < 256; k0 += 32) {
        const short8 af0 = *(const short8*)(Ab0 + k0);
        const short8 af1 = *(const short8*)(Ab1 + k0);
#pragma unroll
        for (int c = 0; c < 4; ++c) {
            const short8 bf = *(const short8*)(Btb + (size_t)c * 16 * 256 + k0);
            a0[c] = __builtin_amdgcn_mfma_f32_16x16x32_bf16(af0, bf, a0[c], 0, 0, 0);
            a1[c] = __builtin_amdgcn_mfma_f32_16x16x32_bf16(af1, bf, a1[c], 0, 0, 0);
        }
    }
    __syncthreads();   // ssum/ssq zero-init visible

#pragma unroll
    for (int c = 0; c < 4; ++c) {
        const int col = c * 16 + l16;
        const float b = bias[col];
        float sc = 0.f, qc = 0.f;
#pragma unroll
        for (int i = 0; i < 4; ++i) {
            const int r0 = m0 + w * 32 + q * 4 + i;
            const int r1 = r0 + 16;
            const float v0 = a0[c][i] + b;
            const float v1 = a1[c][i] + b;
            a0[c][i] = v0;
            a1[c][i] = v1;
            if (r0 < N_NODES) { sc += v0; qc += v0 * v0; }
            if (r1 < N_NODES) { sc += v1; qc += v1 * v1; }
        }
        atomicAdd(&ssum[col], sc);
        atomicAdd(&ssq[col], qc);
    }
    __syncthreads();
    if (t < 64) {
        atomicAdd(&sums[t], ssum[t]);
        atomicAdd(&sums[64 + t], ssq[t]);
    }

    grid.sync();

#pragma unroll
    for (int c = 0; c < 4; ++c) {
        const int col = c * 16 + l16;
        const float mu  = sums[col] * (1.f / N_NODES);
        const float var = sums[64 + col] * (1.f / N_NODES) - mu * mu;
        const float sc2 = rsqrtf(var + BN_EPS) * gamma[col];
        const float be  = beta[col];
#pragma unroll
        for (int i = 0; i < 4; ++i) {
            const int r0 = m0 + w * 32 + q * 4 + i;
            const int r1 = r0 + 16;
            if (r0 < N_NODES) z[(size_t)r0 * 64 + col] = leaky((a0[c][i] - mu) * sc2 + be);
            if (r1 < N_NODES) z[(size_t)r1 * 64 + col] = leaky((a1[c][i] - mu) * sc2 + be);
        }
    }
}

// ---------------------------------------------------------------------------
extern "C" void kernel_launch(void* const* d_in, const int* in_sizes, int n_in,
                              void* d_out, int out_size, void* d_ws, size_t ws_size,
                              hipStream_t stream) {
    const float* feat    = (const float*)d_in[0];
    const int*   src     = (const int*)  d_in[1];
    const int*   dst     = (const int*)  d_in[2];
    const float* W_src   = (const float*)d_in[3];
    const float* b_src   = (const float*)d_in[4];
    const float* W_dst   = (const float*)d_in[5];
    const float* b_dst   = (const float*)d_in[6];
    const float* attn    = (const float*)d_in[7];
    const float* out_bias= (const float*)d_in[8];
    const float* fc_W    = (const float*)d_in[9];
    const float* fc_b    = (const float*)d_in[10];
    const float* gamma   = (const float*)d_in[11];
    const float* beta    = (const float*)d_in[12];
    float* z = (float*)d_out;

    char* ws = (char*)d_ws;
    size_t off = 0;
    auto carve = [&](size_t bytes) -> void* {
        void* p = ws + off;
        off = (off + bytes + 255) & ~(size_t)255;
        return p;
    };
    unsigned short* feat_bf = (unsigned short*)carve((size_t)N_NODES * 256 * 2);
    unsigned short* h_src_bf= (unsigned short*)carve((size_t)N_NODES * 256 * 2);
    unsigned short* h_dst_bf= (unsigned short*)carve((size_t)N_NODES * 256 * 2);
    unsigned short* rst_bf  = (unsigned short*)carve((size_t)N_NODES * 256 * 2);
    unsigned short* WtS     = (unsigned short*)carve((size_t)256 * 256 * 2);
    unsigned short* WtD     = (unsigned short*)carve((size_t)256 * 256 * 2);
    unsigned short* WtF     = (unsigned short*)carve((size_t)64 * 256 * 2);
    int*   srcl   = (int*)  carve((size_t)N_EDGES * 4);
    int*   cnt2   = (int*)  carve((size_t)2 * N_NODES * 4);
    int*   offs   = (int*)  carve((size_t)(N_NODES + 1) * 4);
    int*   bsum   = (int*)  carve(256 * 4);
    int*   bpre   = (int*)  carve(256 * 4);
    float* sums   = (float*)carve(128 * 4);

    // 1. cooperative prep + CSR build (replaces 5 dispatches)
    {
        void* args[] = {(void*)&feat, (void*)&W_src, (void*)&W_dst, (void*)&fc_W,
                        (void*)&src, (void*)&dst,
                        (void*)&feat_bf, (void*)&WtS, (void*)&WtD, (void*)&WtF,
                        (void*)&cnt2, (void*)&sums, (void*)&offs, (void*)&bsum,
                        (void*)&bpre, (void*)&srcl};
        hipLaunchCooperativeKernel((void*)prep_csr_kernel, dim3(784), dim3(256),
                                   args, 0, stream);
    }

    // 2. dual input projection (bf16 MFMA, fragment-ordered LDS)
    proj_kernel<<<dim3((N_NODES + 127) / 128, 4), 256, 0, stream>>>(
        feat_bf, WtS, WtD, b_src, b_dst, h_src_bf, h_dst_bf);

    // 3. fused score + softmax + aggregation (1 wave per node)
    agg_fused_kernel<<<N_NODES / 4, 256, 0, stream>>>(h_src_bf, h_dst_bf, srcl, offs,
                                                      attn, out_bias, rst_bf);

    // 4. cooperative fc + BatchNorm + LeakyReLU (replaces 2 dispatches)
    {
        void* args[] = {(void*)&rst_bf, (void*)&WtF, (void*)&fc_b, (void*)&z,
                        (void*)&sums, (void*)&gamma, (void*)&beta};
        hipLaunchCooperativeKernel((void*)fcbn_kernel, dim3((N_NODES + 127) / 128),
                                   dim3(256), args, 0, stream);
    }
}

// Round 11
// 367.800 us; speedup vs baseline: 2.2490x; 2.2490x over previous
//
#include <hip/hip_runtime.h>
#include <math.h>

#define N_NODES 50000
#define N_EDGES 800000
#define HD 256          // NHEAD * OUT_DIM
#define OUT_DIM 64
#define NHEAD 4
#define SLOPE 0.2f
#define BN_EPS 1e-5f
#define LOG2E 1.4426950408889634f

typedef __attribute__((ext_vector_type(8))) short short8;
typedef __attribute__((ext_vector_type(4))) float float4v;

__device__ __forceinline__ float leaky(float x) { return x >= 0.f ? x : SLOPE * x; }

__device__ __forceinline__ float bf2f(unsigned short u) {
    return __uint_as_float(((unsigned)u) << 16);
}
__device__ __forceinline__ unsigned short f2bf(float f) {
    unsigned u = __float_as_uint(f);
    unsigned r = (u + 0x7fffu + ((u >> 16) & 1u)) >> 16;
    return (unsigned short)r;
}

// 16-lane-group sum via DPP row rotations (pure VALU, no LDS pipe).
// row_ror:k ctrl = 0x120 + k; rotations by 1,2,4,8 within the 16-lane row
// give every lane the full group sum.
template <int CTRL>
__device__ __forceinline__ float ror_add(float v) {
    const int r = __builtin_amdgcn_update_dpp(0, __float_as_int(v), CTRL, 0xF, 0xF, true);
    return v + __int_as_float(r);
}
__device__ __forceinline__ float group16_sum(float v) {
    v = ror_add<0x121>(v);
    v = ror_add<0x122>(v);
    v = ror_add<0x124>(v);
    v = ror_add<0x128>(v);
    return v;
}

// ---------------------------------------------------------------------------
// prep: feat fp32->bf16 cast, 3 weight transpose+casts, zero cnt/cursor/sums.
// ---------------------------------------------------------------------------
__global__ __launch_bounds__(256) void prep_kernel(const float* __restrict__ feat,
                                                   const float* __restrict__ W_src,
                                                   const float* __restrict__ W_dst,
                                                   const float* __restrict__ fc_W,
                                                   unsigned short* __restrict__ feat_bf,
                                                   unsigned short* __restrict__ WtS,
                                                   unsigned short* __restrict__ WtD,
                                                   unsigned short* __restrict__ WtF,
                                                   int* __restrict__ cnt2,
                                                   float* __restrict__ sums) {
    const int b = blockIdx.x;
    const int t = threadIdx.x;
    if (b < 12500) {
        const int i = b * 256 + t;
        const float4 v = ((const float4*)feat)[i];
        ushort4 o;
        o.x = f2bf(v.x); o.y = f2bf(v.y); o.z = f2bf(v.z); o.w = f2bf(v.w);
        ((ushort4*)feat_bf)[i] = o;
    } else if (b < 12756) {
        const int n = b - 12500;
        WtS[(size_t)n * 256 + t] = f2bf(W_src[(size_t)t * 256 + n]);
    } else if (b < 13012) {
        const int n = b - 12756;
        WtD[(size_t)n * 256 + t] = f2bf(W_dst[(size_t)t * 256 + n]);
    } else if (b < 13076) {
        const int n = b - 13012;
        WtF[(size_t)n * 256 + t] = f2bf(fc_W[(size_t)t * 64 + n]);
    } else if (b < 13174) {
        const int i = (b - 13076) * 256 + t;
        if (i < 25000) ((int4*)cnt2)[i] = make_int4(0, 0, 0, 0);
    } else {
        if (t < 128) sums[t] = 0.f;
    }
}

// ---------------------------------------------------------------------------
// Dual-output bf16 MFMA GEMM, fragment-ordered LDS (64 KB for both B chunks).
// Grid (391, 4): 128 rows x 64 cols of BOTH outputs. Each fragment is one
// conflict-free ds_read_b128. A: 16 fragments prefetched to registers.
// ---------------------------------------------------------------------------
__global__ __launch_bounds__(256) void proj_kernel(const unsigned short* __restrict__ A,
                                                   const unsigned short* __restrict__ BtS,
                                                   const unsigned short* __restrict__ BtD,
                                                   const float* __restrict__ bS,
                                                   const float* __restrict__ bD,
                                                   unsigned short* __restrict__ CS,
                                                   unsigned short* __restrict__ CD) {
    __shared__ unsigned short Bs[2][64 * 256];   // fragment-ordered, 64 KB

    const int t    = threadIdx.x;
    const int w    = t >> 6;
    const int lane = t & 63;
    const int q    = lane >> 4;
    const int l16  = lane & 15;
    const int m0   = blockIdx.x * 128;
    const int c0   = blockIdx.y * 64;

    // ---- A prefetch ----
    int ar0 = m0 + w * 32 + l16;
    int ar1 = ar0 + 16;
    if (ar0 > N_NODES - 1) ar0 = N_NODES - 1;
    if (ar1 > N_NODES - 1) ar1 = N_NODES - 1;
    const unsigned short* Ab0 = A + (size_t)ar0 * 256 + q * 8;
    const unsigned short* Ab1 = A + (size_t)ar1 * 256 + q * 8;
    short8 afr0[8], afr1[8];
#pragma unroll
    for (int kk = 0; kk < 8; ++kk) {
        afr0[kk] = *(const short8*)(Ab0 + kk * 32);
        afr1[kk] = *(const short8*)(Ab1 + kk * 32);
    }

    // ---- stage both B chunks, fragment order ----
    {
        const int r   = t >> 2;        // B row (= output col) 0..63
        const int seg = t & 3;
        const int c   = r >> 4;
        const int L   = r & 15;
        const unsigned short* gS = BtS + (size_t)(c0 + r) * 256 + seg * 64;
        const unsigned short* gD = BtD + (size_t)(c0 + r) * 256 + seg * 64;
#pragma unroll
        for (int kk2 = 0; kk2 < 2; ++kk2) {
            const int kk = seg * 2 + kk2;
#pragma unroll
            for (int q2 = 0; q2 < 4; ++q2) {
                *(short8*)(&Bs[0][((c * 8 + kk) * 64 + q2 * 16 + L) * 8]) =
                    *(const short8*)(gS + kk2 * 32 + q2 * 8);
                *(short8*)(&Bs[1][((c * 8 + kk) * 64 + q2 * 16 + L) * 8]) =
                    *(const short8*)(gD + kk2 * 32 + q2 * 8);
            }
        }
    }
    __syncthreads();

    float4v aS0[4] = {}, aS1[4] = {}, aD0[4] = {}, aD1[4] = {};

#pragma unroll
    for (int kk = 0; kk < 8; ++kk) {
        const short8 af0 = afr0[kk];
        const short8 af1 = afr1[kk];
#pragma unroll
        for (int c = 0; c < 4; ++c) {
            const short8 bs = *(const short8*)(&Bs[0][((c * 8 + kk) * 64 + lane) * 8]);
            aS0[c] = __builtin_amdgcn_mfma_f32_16x16x32_bf16(af0, bs, aS0[c], 0, 0, 0);
            aS1[c] = __builtin_amdgcn_mfma_f32_16x16x32_bf16(af1, bs, aS1[c], 0, 0, 0);
            const short8 bd = *(const short8*)(&Bs[1][((c * 8 + kk) * 64 + lane) * 8]);
            aD0[c] = __builtin_amdgcn_mfma_f32_16x16x32_bf16(af0, bd, aD0[c], 0, 0, 0);
            aD1[c] = __builtin_amdgcn_mfma_f32_16x16x32_bf16(af1, bd, aD1[c], 0, 0, 0);
        }
    }

#pragma unroll
    for (int c = 0; c < 4; ++c) {
        const int col = c0 + c * 16 + l16;
        const float vbS = bS[col];
        const float vbD = bD[col];
#pragma unroll
        for (int i = 0; i < 4; ++i) {
            const int r0 = m0 + w * 32 + q * 4 + i;
            const int r1 = r0 + 16;
            if (r0 < N_NODES) {
                CS[(size_t)r0 * 256 + col] = f2bf(aS0[c][i] + vbS);
                CD[(size_t)r0 * 256 + col] = f2bf(aD0[c][i] + vbD);
            }
            if (r1 < N_NODES) {
                CS[(size_t)r1 * 256 + col] = f2bf(aS1[c][i] + vbS);
                CD[(size_t)r1 * 256 + col] = f2bf(aD1[c][i] + vbD);
            }
        }
    }
}

// ---------------------------------------------------------------------------
// fc GEMM (bf16 MFMA, fp32 out) + fused BatchNorm partial-stats epilogue.
// ---------------------------------------------------------------------------
__global__ __launch_bounds__(256) void fc_bn_kernel(const unsigned short* __restrict__ A,
                                                    const unsigned short* __restrict__ Bt,
                                                    const float* __restrict__ bias,
                                                    float* __restrict__ C,
                                                    float* __restrict__ sums,
                                                    int M) {
    const int w    = threadIdx.x >> 6;
    const int lane = threadIdx.x & 63;
    const int q    = lane >> 4;
    const int l16  = lane & 15;
    const int m0   = blockIdx.x * 64;
    const int t    = threadIdx.x;

    __shared__ float ssum[64], ssq[64];
    if (t < 64) { ssum[t] = 0.f; ssq[t] = 0.f; }

    int arow = m0 + w * 16 + l16;
    if (arow > M - 1) arow = M - 1;
    const unsigned short* Ab  = A  + (size_t)arow * 256 + q * 8;
    const unsigned short* Btb = Bt + (size_t)l16 * 256 + q * 8;

    float4v acc[4] = {};

    for (int k0 = 0; k0 < 256; k0 += 32) {
        const short8 af = *(const short8*)(Ab + k0);
#pragma unroll
        for (int c = 0; c < 4; ++c) {
            const short8 bf = *(const short8*)(Btb + (size_t)c * 16 * 256 + k0);
            acc[c] = __builtin_amdgcn_mfma_f32_16x16x32_bf16(af, bf, acc[c], 0, 0, 0);
        }
    }
    __syncthreads();

#pragma unroll
    for (int c = 0; c < 4; ++c) {
        const int col = c * 16 + l16;
        const float b = bias[col];
        float s = 0.f, qq = 0.f;
#pragma unroll
        for (int i = 0; i < 4; ++i) {
            const int r = m0 + w * 16 + q * 4 + i;
            if (r < M) {
                const float v = acc[c][i] + b;
                C[(size_t)r * 64 + col] = v;
                s += v;
                qq += v * v;
            }
        }
        atomicAdd(&ssum[col], s);
        atomicAdd(&ssq[col], qq);
    }
    __syncthreads();
    if (t < 64) {
        atomicAdd(&sums[t], ssum[t]);
        atomicAdd(&sums[64 + t], ssq[t]);
    }
}

// ---------------------------------------------------------------------------
// CSR build: histogram, 2-phase scan, scatter.
// ---------------------------------------------------------------------------
__global__ void hist_kernel(const int* __restrict__ dst, int* __restrict__ cnt) {
    const int i = blockIdx.x * 256 + threadIdx.x;
    if (i < N_EDGES) atomicAdd(&cnt[dst[i]], 1);
}

__global__ __launch_bounds__(512) void scan1_kernel(const int* __restrict__ cnt,
                                                    int* __restrict__ offs,
                                                    int* __restrict__ bsum) {
    __shared__ int s[512];
    const int t = threadIdx.x;
    const int i = blockIdx.x * 512 + t;
    const int v = (i < N_NODES) ? cnt[i] : 0;
    s[t] = v;
    __syncthreads();
    for (int off = 1; off < 512; off <<= 1) {
        const int x = (t >= off) ? s[t - off] : 0;
        __syncthreads();
        s[t] += x;
        __syncthreads();
    }
    if (i < N_NODES) offs[i] = s[t] - v;
    if (t == 511) bsum[blockIdx.x] = s[511];
}

__global__ __launch_bounds__(128) void scan2_kernel(const int* __restrict__ bsum,
                                                    int* __restrict__ bpre,
                                                    int nblk) {
    __shared__ int s[128];
    const int t = threadIdx.x;
    const int v = (t < nblk) ? bsum[t] : 0;
    s[t] = v;
    __syncthreads();
    for (int off = 1; off < 128; off <<= 1) {
        const int x = (t >= off) ? s[t - off] : 0;
        __syncthreads();
        s[t] += x;
        __syncthreads();
    }
    if (t < 128) bpre[t] = s[t] - v;
}

__global__ void scatter_kernel(const int* __restrict__ src,
                               const int* __restrict__ dst,
                               const int* __restrict__ offs,
                               const int* __restrict__ bpre,
                               int* __restrict__ cursor,
                               int* __restrict__ srcl) {
    const int i = blockIdx.x * 256 + threadIdx.x;
    if (i < N_EDGES) {
        const int d = dst[i];
        const int p = offs[d] + bpre[d >> 9] + atomicAdd(&cursor[d], 1);
        srcl[p] = src[i];
    }
}

// ---------------------------------------------------------------------------
// Fused GATv2 score + softmax + aggregation: one wave per node, one edge per
// wave-iteration (lane l = dims 4l..4l+3; 16-lane group == head).
// Group score reduction via DPP rotation adds (VALU) instead of ds_swizzle.
// No-max exponentials (|e| << 88 for this data; exactly softmax).
// ---------------------------------------------------------------------------
__global__ __launch_bounds__(256) void agg_fused_kernel(const unsigned short* __restrict__ h_src,
                                                        const unsigned short* __restrict__ h_dst,
                                                        const int* __restrict__ srcl,
                                                        const int* __restrict__ offs,
                                                        const int* __restrict__ bpre,
                                                        const float* __restrict__ attn,
                                                        const float* __restrict__ out_bias,
                                                        unsigned short* __restrict__ rst) {
    const int node = blockIdx.x * 4 + (threadIdx.x >> 6);
    const int lane = threadIdx.x & 63;
    const int d4 = lane * 4;

    const int beg = offs[node] + bpre[node >> 9];
    const int end = (node + 1 == N_NODES) ? N_EDGES
                                          : (offs[node + 1] + bpre[(node + 1) >> 9]);

    const ushort4 hdv = *(const ushort4*)(h_dst + (size_t)node * 256 + d4);
    const float hd0 = bf2f(hdv.x), hd1 = bf2f(hdv.y), hd2 = bf2f(hdv.z), hd3 = bf2f(hdv.w);
    const float4 araw = *(const float4*)(attn + d4);
    const float av0 = araw.x * LOG2E, av1 = araw.y * LOG2E,
                av2 = araw.z * LOG2E, av3 = araw.w * LOG2E;
    const float aw0 = av0 * SLOPE, aw1 = av1 * SLOPE,
                aw2 = av2 * SLOPE, aw3 = av3 * SLOPE;

    float wsum = 0.f, a0 = 0.f, a1 = 0.f, a2 = 0.f, a3 = 0.f;

    int p = beg;
    for (; p + 2 <= end; p += 2) {
        const int s0 = srcl[p];
        const int s1 = srcl[p + 1];
        const ushort4 va = *(const ushort4*)(h_src + (size_t)s0 * 256 + d4);
        const ushort4 vb = *(const ushort4*)(h_src + (size_t)s1 * 256 + d4);

        const float ra0 = bf2f(va.x), ra1 = bf2f(va.y), ra2 = bf2f(va.z), ra3 = bf2f(va.w);
        const float rb0 = bf2f(vb.x), rb1 = bf2f(vb.y), rb2 = bf2f(vb.z), rb3 = bf2f(vb.w);

        const float ya0 = ra0 + hd0, ya1 = ra1 + hd1, ya2 = ra2 + hd2, ya3 = ra3 + hd3;
        const float yb0 = rb0 + hd0, yb1 = rb1 + hd1, yb2 = rb2 + hd2, yb3 = rb3 + hd3;

        float pa = av0 * fmaxf(ya0, 0.f) + aw0 * fminf(ya0, 0.f);
        pa = fmaf(av1, fmaxf(ya1, 0.f), fmaf(aw1, fminf(ya1, 0.f), pa));
        pa = fmaf(av2, fmaxf(ya2, 0.f), fmaf(aw2, fminf(ya2, 0.f), pa));
        pa = fmaf(av3, fmaxf(ya3, 0.f), fmaf(aw3, fminf(ya3, 0.f), pa));
        float pb = av0 * fmaxf(yb0, 0.f) + aw0 * fminf(yb0, 0.f);
        pb = fmaf(av1, fmaxf(yb1, 0.f), fmaf(aw1, fminf(yb1, 0.f), pb));
        pb = fmaf(av2, fmaxf(yb2, 0.f), fmaf(aw2, fminf(yb2, 0.f), pb));
        pb = fmaf(av3, fmaxf(yb3, 0.f), fmaf(aw3, fminf(yb3, 0.f), pb));

        pa = group16_sum(pa);
        pb = group16_sum(pb);

        const float wa = __builtin_amdgcn_exp2f(pa);
        const float wb = __builtin_amdgcn_exp2f(pb);
        wsum += wa + wb;
        a0 = fmaf(wa, ra0, fmaf(wb, rb0, a0));
        a1 = fmaf(wa, ra1, fmaf(wb, rb1, a1));
        a2 = fmaf(wa, ra2, fmaf(wb, rb2, a2));
        a3 = fmaf(wa, ra3, fmaf(wb, rb3, a3));
    }
    if (p < end) {
        const int s0 = srcl[p];
        const ushort4 va = *(const ushort4*)(h_src + (size_t)s0 * 256 + d4);
        const float ra0 = bf2f(va.x), ra1 = bf2f(va.y), ra2 = bf2f(va.z), ra3 = bf2f(va.w);
        const float ya0 = ra0 + hd0, ya1 = ra1 + hd1, ya2 = ra2 + hd2, ya3 = ra3 + hd3;
        float pa = av0 * fmaxf(ya0, 0.f) + aw0 * fminf(ya0, 0.f);
        pa = fmaf(av1, fmaxf(ya1, 0.f), fmaf(aw1, fminf(ya1, 0.f), pa));
        pa = fmaf(av2, fmaxf(ya2, 0.f), fmaf(aw2, fminf(ya2, 0.f), pa));
        pa = fmaf(av3, fmaxf(ya3, 0.f), fmaf(aw3, fminf(ya3, 0.f), pa));
        pa = group16_sum(pa);
        const float wa = __builtin_amdgcn_exp2f(pa);
        wsum += wa;
        a0 = fmaf(wa, ra0, a0);
        a1 = fmaf(wa, ra1, a1);
        a2 = fmaf(wa, ra2, a2);
        a3 = fmaf(wa, ra3, a3);
    }

    const float inv = (wsum > 0.f) ? 1.f / wsum : 0.f;
    const float4 ob = *(const float4*)(out_bias + d4);
    ushort4 o;
    o.x = f2bf(fmaf(a0, inv, ob.x));
    o.y = f2bf(fmaf(a1, inv, ob.y));
    o.z = f2bf(fmaf(a2, inv, ob.z));
    o.w = f2bf(fmaf(a3, inv, ob.w));
    *(ushort4*)(rst + (size_t)node * 256 + d4) = o;
}

// ---------------------------------------------------------------------------
// BatchNorm finalize + LeakyReLU
// ---------------------------------------------------------------------------
__global__ void bn_final_kernel(float* __restrict__ z,
                                const float* __restrict__ sums,
                                const float* __restrict__ gamma,
                                const float* __restrict__ beta) {
    const int i = blockIdx.x * 256 + threadIdx.x;
    if (i < N_NODES * 64) {
        const int col = i & 63;
        const float mu  = sums[col] * (1.f / N_NODES);
        const float var = sums[64 + col] * (1.f / N_NODES) - mu * mu;
        const float v = (z[i] - mu) * rsqrtf(var + BN_EPS) * gamma[col] + beta[col];
        z[i] = leaky(v);
    }
}

// ---------------------------------------------------------------------------
extern "C" void kernel_launch(void* const* d_in, const int* in_sizes, int n_in,
                              void* d_out, int out_size, void* d_ws, size_t ws_size,
                              hipStream_t stream) {
    const float* feat    = (const float*)d_in[0];
    const int*   src     = (const int*)  d_in[1];
    const int*   dst     = (const int*)  d_in[2];
    const float* W_src   = (const float*)d_in[3];
    const float* b_src   = (const float*)d_in[4];
    const float* W_dst   = (const float*)d_in[5];
    const float* b_dst   = (const float*)d_in[6];
    const float* attn    = (const float*)d_in[7];
    const float* out_bias= (const float*)d_in[8];
    const float* fc_W    = (const float*)d_in[9];
    const float* fc_b    = (const float*)d_in[10];
    const float* gamma   = (const float*)d_in[11];
    const float* beta    = (const float*)d_in[12];
    float* z = (float*)d_out;

    char* ws = (char*)d_ws;
    size_t off = 0;
    auto carve = [&](size_t bytes) -> void* {
        void* p = ws + off;
        off = (off + bytes + 255) & ~(size_t)255;
        return p;
    };
    unsigned short* feat_bf = (unsigned short*)carve((size_t)N_NODES * 256 * 2);
    unsigned short* h_src_bf= (unsigned short*)carve((size_t)N_NODES * 256 * 2);
    unsigned short* h_dst_bf= (unsigned short*)carve((size_t)N_NODES * 256 * 2);
    unsigned short* rst_bf  = (unsigned short*)carve((size_t)N_NODES * 256 * 2);
    unsigned short* WtS     = (unsigned short*)carve((size_t)256 * 256 * 2);
    unsigned short* WtD     = (unsigned short*)carve((size_t)256 * 256 * 2);
    unsigned short* WtF     = (unsigned short*)carve((size_t)64 * 256 * 2);
    int*   srcl   = (int*)  carve((size_t)N_EDGES * 4);
    int*   cnt    = (int*)  carve((size_t)2 * N_NODES * 4);
    int*   cursor = cnt + N_NODES;
    int*   offs   = (int*)  carve((size_t)(N_NODES + 1) * 4);
    int*   bsum   = (int*)  carve(128 * 4);
    int*   bpre   = (int*)  carve(128 * 4);
    float* sums   = (float*)carve(128 * 4);

    const int nchunks = (N_NODES + 511) / 512;      // 98

    // prep: cast + transposes + zeroing
    prep_kernel<<<13175, 256, 0, stream>>>(feat, W_src, W_dst, fc_W,
                                           feat_bf, WtS, WtD, WtF, cnt, sums);

    // dual input projection (bf16 MFMA, fragment-ordered LDS)
    proj_kernel<<<dim3((N_NODES + 127) / 128, 4), 256, 0, stream>>>(
        feat_bf, WtS, WtD, b_src, b_dst, h_src_bf, h_dst_bf);

    // CSR by dst
    hist_kernel<<<(N_EDGES + 255) / 256, 256, 0, stream>>>(dst, cnt);
    scan1_kernel<<<nchunks, 512, 0, stream>>>(cnt, offs, bsum);
    scan2_kernel<<<1, 128, 0, stream>>>(bsum, bpre, nchunks);
    scatter_kernel<<<(N_EDGES + 255) / 256, 256, 0, stream>>>(src, dst, offs, bpre, cursor, srcl);

    // fused score + softmax + aggregation (1 wave per node, DPP reductions)
    agg_fused_kernel<<<N_NODES / 4, 256, 0, stream>>>(h_src_bf, h_dst_bf, srcl, offs, bpre,
                                                      attn, out_bias, rst_bf);

    // trailing fc + BN partial stats
    fc_bn_kernel<<<(N_NODES + 63) / 64, 256, 0, stream>>>(rst_bf, WtF, fc_b, z, sums, N_NODES);

    // batchnorm finalize + leaky
    bn_final_kernel<<<(N_NODES * 64 + 255) / 256, 256, 0, stream>>>(z, sums, gamma, beta);
}

// Round 12
// 361.215 us; speedup vs baseline: 2.2900x; 1.0182x over previous
//
#include <hip/hip_runtime.h>
#include <math.h>

#define N_NODES 50000
#define N_EDGES 800000
#define HD 256          // NHEAD * OUT_DIM
#define OUT_DIM 64
#define NHEAD 4
#define SLOPE 0.2f
#define BN_EPS 1e-5f
#define LOG2E 1.4426950408889634f
#define NTILES 391      // ceil(N_NODES / 128)

typedef __attribute__((ext_vector_type(8))) short short8;
typedef __attribute__((ext_vector_type(4))) float float4v;

__device__ __forceinline__ float leaky(float x) { return x >= 0.f ? x : SLOPE * x; }

__device__ __forceinline__ float bf2f(unsigned short u) {
    return __uint_as_float(((unsigned)u) << 16);
}
__device__ __forceinline__ unsigned short f2bf(float f) {
    unsigned u = __float_as_uint(f);
    unsigned r = (u + 0x7fffu + ((u >> 16) & 1u)) >> 16;
    return (unsigned short)r;
}

// 16-lane-group sum via DPP row rotations (pure VALU, no LDS pipe).
template <int CTRL>
__device__ __forceinline__ float ror_add(float v) {
    const int r = __builtin_amdgcn_update_dpp(0, __float_as_int(v), CTRL, 0xF, 0xF, true);
    return v + __int_as_float(r);
}
__device__ __forceinline__ float group16_sum(float v) {
    v = ror_add<0x121>(v);
    v = ror_add<0x122>(v);
    v = ror_add<0x124>(v);
    v = ror_add<0x128>(v);
    return v;
}

// ---------------------------------------------------------------------------
// prep: feat fp32->bf16 cast, 3 weight transpose+casts, zero cnt/cursor/sums/done.
// ---------------------------------------------------------------------------
__global__ __launch_bounds__(256) void prep_kernel(const float* __restrict__ feat,
                                                   const float* __restrict__ W_src,
                                                   const float* __restrict__ W_dst,
                                                   const float* __restrict__ fc_W,
                                                   unsigned short* __restrict__ feat_bf,
                                                   unsigned short* __restrict__ WtS,
                                                   unsigned short* __restrict__ WtD,
                                                   unsigned short* __restrict__ WtF,
                                                   int* __restrict__ cnt2,
                                                   float* __restrict__ sums,
                                                   int* __restrict__ done) {
    const int b = blockIdx.x;
    const int t = threadIdx.x;
    if (b < 12500) {
        const int i = b * 256 + t;
        const float4 v = ((const float4*)feat)[i];
        ushort4 o;
        o.x = f2bf(v.x); o.y = f2bf(v.y); o.z = f2bf(v.z); o.w = f2bf(v.w);
        ((ushort4*)feat_bf)[i] = o;
    } else if (b < 12756) {
        const int n = b - 12500;
        WtS[(size_t)n * 256 + t] = f2bf(W_src[(size_t)t * 256 + n]);
    } else if (b < 13012) {
        const int n = b - 12756;
        WtD[(size_t)n * 256 + t] = f2bf(W_dst[(size_t)t * 256 + n]);
    } else if (b < 13076) {
        const int n = b - 13012;
        WtF[(size_t)n * 256 + t] = f2bf(fc_W[(size_t)t * 64 + n]);
    } else if (b < 13174) {
        const int i = (b - 13076) * 256 + t;
        if (i < 25000) ((int4*)cnt2)[i] = make_int4(0, 0, 0, 0);
    } else {
        if (t < 128) sums[t] = 0.f;
        if (t == 128) done[0] = 0;
    }
}

// ---------------------------------------------------------------------------
// Persistent-B bf16 MFMA GEMM. Grid (98, 8): y&3 = 64-col chunk, y>>2 = S/D.
// Block stages its 32 KB B chunk ONCE (fragment-ordered -> conflict-free
// ds_read_b128), then loops over row-tiles with no further barriers.
// ---------------------------------------------------------------------------
__global__ __launch_bounds__(256) void proj_kernel(const unsigned short* __restrict__ A,
                                                   const unsigned short* __restrict__ BtS,
                                                   const unsigned short* __restrict__ BtD,
                                                   const float* __restrict__ bS,
                                                   const float* __restrict__ bD,
                                                   unsigned short* __restrict__ CS,
                                                   unsigned short* __restrict__ CD) {
    __shared__ unsigned short Bs[64 * 256];   // 32 KB, fragment-ordered

    const int t    = threadIdx.x;
    const int w    = t >> 6;
    const int lane = t & 63;
    const int q    = lane >> 4;
    const int l16  = lane & 15;
    const int c0   = (blockIdx.y & 3) * 64;
    const bool isD = (blockIdx.y >= 4);

    const unsigned short* Bt   = isD ? BtD : BtS;
    const float*          bias = isD ? bD  : bS;
    unsigned short*       C    = isD ? CD  : CS;

    // ---- stage B chunk once, fragment order ----
    {
        const int r   = t >> 2;        // B row (= output col) 0..63
        const int seg = t & 3;
        const int c   = r >> 4;
        const int L   = r & 15;
        const unsigned short* g = Bt + (size_t)(c0 + r) * 256 + seg * 64;
#pragma unroll
        for (int kk2 = 0; kk2 < 2; ++kk2) {
            const int kk = seg * 2 + kk2;
#pragma unroll
            for (int q2 = 0; q2 < 4; ++q2)
                *(short8*)(&Bs[((c * 8 + kk) * 64 + q2 * 16 + L) * 8]) =
                    *(const short8*)(g + kk2 * 32 + q2 * 8);
        }
    }
    __syncthreads();

    float vb[4];
#pragma unroll
    for (int c = 0; c < 4; ++c) vb[c] = bias[c0 + c * 16 + l16];

    // ---- persistent loop over row tiles (no barriers inside) ----
    for (int tile = blockIdx.x; tile < NTILES; tile += 98) {
        const int m0 = tile * 128;

        int ar0 = m0 + w * 32 + l16;
        int ar1 = ar0 + 16;
        if (ar0 > N_NODES - 1) ar0 = N_NODES - 1;
        if (ar1 > N_NODES - 1) ar1 = N_NODES - 1;
        const unsigned short* Ab0 = A + (size_t)ar0 * 256 + q * 8;
        const unsigned short* Ab1 = A + (size_t)ar1 * 256 + q * 8;
        short8 afr0[8], afr1[8];
#pragma unroll
        for (int kk = 0; kk < 8; ++kk) {
            afr0[kk] = *(const short8*)(Ab0 + kk * 32);
            afr1[kk] = *(const short8*)(Ab1 + kk * 32);
        }

        float4v a0[4] = {}, a1[4] = {};
#pragma unroll
        for (int kk = 0; kk < 8; ++kk) {
            const short8 af0 = afr0[kk];
            const short8 af1 = afr1[kk];
#pragma unroll
            for (int c = 0; c < 4; ++c) {
                const short8 b = *(const short8*)(&Bs[((c * 8 + kk) * 64 + lane) * 8]);
                a0[c] = __builtin_amdgcn_mfma_f32_16x16x32_bf16(af0, b, a0[c], 0, 0, 0);
                a1[c] = __builtin_amdgcn_mfma_f32_16x16x32_bf16(af1, b, a1[c], 0, 0, 0);
            }
        }

#pragma unroll
        for (int c = 0; c < 4; ++c) {
            const int col = c0 + c * 16 + l16;
#pragma unroll
            for (int i = 0; i < 4; ++i) {
                const int r0 = m0 + w * 32 + q * 4 + i;
                const int r1 = r0 + 16;
                if (r0 < N_NODES) C[(size_t)r0 * 256 + col] = f2bf(a0[c][i] + vb[c]);
                if (r1 < N_NODES) C[(size_t)r1 * 256 + col] = f2bf(a1[c][i] + vb[c]);
            }
        }
    }
}

// ---------------------------------------------------------------------------
// fc GEMM (bf16 MFMA, fp32 out) + fused BatchNorm partial-stats epilogue.
// ---------------------------------------------------------------------------
__global__ __launch_bounds__(256) void fc_bn_kernel(const unsigned short* __restrict__ A,
                                                    const unsigned short* __restrict__ Bt,
                                                    const float* __restrict__ bias,
                                                    float* __restrict__ C,
                                                    float* __restrict__ sums,
                                                    int M) {
    const int w    = threadIdx.x >> 6;
    const int lane = threadIdx.x & 63;
    const int q    = lane >> 4;
    const int l16  = lane & 15;
    const int m0   = blockIdx.x * 64;
    const int t    = threadIdx.x;

    __shared__ float ssum[64], ssq[64];
    if (t < 64) { ssum[t] = 0.f; ssq[t] = 0.f; }

    int arow = m0 + w * 16 + l16;
    if (arow > M - 1) arow = M - 1;
    const unsigned short* Ab  = A  + (size_t)arow * 256 + q * 8;
    const unsigned short* Btb = Bt + (size_t)l16 * 256 + q * 8;

    float4v acc[4] = {};

    for (int k0 = 0; k0 < 256; k0 += 32) {
        const short8 af = *(const short8*)(Ab + k0);
#pragma unroll
        for (int c = 0; c < 4; ++c) {
            const short8 bf = *(const short8*)(Btb + (size_t)c * 16 * 256 + k0);
            acc[c] = __builtin_amdgcn_mfma_f32_16x16x32_bf16(af, bf, acc[c], 0, 0, 0);
        }
    }
    __syncthreads();

#pragma unroll
    for (int c = 0; c < 4; ++c) {
        const int col = c * 16 + l16;
        const float b = bias[col];
        float s = 0.f, qq = 0.f;
#pragma unroll
        for (int i = 0; i < 4; ++i) {
            const int r = m0 + w * 16 + q * 4 + i;
            if (r < M) {
                const float v = acc[c][i] + b;
                C[(size_t)r * 64 + col] = v;
                s += v;
                qq += v * v;
            }
        }
        atomicAdd(&ssum[col], s);
        atomicAdd(&ssq[col], qq);
    }
    __syncthreads();
    if (t < 64) {
        atomicAdd(&sums[t], ssum[t]);
        atomicAdd(&sums[64 + t], ssq[t]);
    }
}

// ---------------------------------------------------------------------------
// CSR build: histogram; merged 2-level scan (last-block does chunk-sum scan);
// scatter.
// ---------------------------------------------------------------------------
__global__ void hist_kernel(const int* __restrict__ dst, int* __restrict__ cnt) {
    const int i = blockIdx.x * 256 + threadIdx.x;
    if (i < N_EDGES) atomicAdd(&cnt[dst[i]], 1);
}

__global__ __launch_bounds__(512) void scan_kernel(const int* __restrict__ cnt,
                                                   int* __restrict__ offs,
                                                   int* __restrict__ bsum,
                                                   int* __restrict__ bpre,
                                                   int* __restrict__ done) {
    __shared__ int s[512];
    __shared__ bool amLast;
    const int t = threadIdx.x;
    const int i = blockIdx.x * 512 + t;
    const int v = (i < N_NODES) ? cnt[i] : 0;
    s[t] = v;
    __syncthreads();
    for (int off = 1; off < 512; off <<= 1) {
        const int x = (t >= off) ? s[t - off] : 0;
        __syncthreads();
        s[t] += x;
        __syncthreads();
    }
    if (i < N_NODES) offs[i] = s[t] - v;       // exclusive within chunk
    if (t == 511) {
        bsum[blockIdx.x] = s[511];
        __threadfence();
        amLast = (atomicAdd(done, 1) == (int)gridDim.x - 1);
    }
    __syncthreads();
    if (amLast) {
        const int v2 = (t < (int)gridDim.x) ? atomicAdd(&bsum[t], 0) : 0;
        s[t] = v2;
        __syncthreads();
        for (int off = 1; off < 512; off <<= 1) {
            const int x = (t >= off) ? s[t - off] : 0;
            __syncthreads();
            s[t] += x;
            __syncthreads();
        }
        if (t < (int)gridDim.x) bpre[t] = s[t] - v2;
    }
}

__global__ void scatter_kernel(const int* __restrict__ src,
                               const int* __restrict__ dst,
                               const int* __restrict__ offs,
                               const int* __restrict__ bpre,
                               int* __restrict__ cursor,
                               int* __restrict__ srcl) {
    const int i = blockIdx.x * 256 + threadIdx.x;
    if (i < N_EDGES) {
        const int d = dst[i];
        const int p = offs[d] + bpre[d >> 9] + atomicAdd(&cursor[d], 1);
        srcl[p] = src[i];
    }
}

// ---------------------------------------------------------------------------
// Fused GATv2 score + softmax + aggregation: one wave per node. Unroll x4;
// src ids moved to SGPRs via readfirstlane so gathers are saddr-form.
// DPP group reductions; no-max exponentials (|e| << 88; exactly softmax).
// ---------------------------------------------------------------------------
__global__ __launch_bounds__(256) void agg_fused_kernel(const unsigned short* __restrict__ h_src,
                                                        const unsigned short* __restrict__ h_dst,
                                                        const int* __restrict__ srcl,
                                                        const int* __restrict__ offs,
                                                        const int* __restrict__ bpre,
                                                        const float* __restrict__ attn,
                                                        const float* __restrict__ out_bias,
                                                        unsigned short* __restrict__ rst) {
    const int node = blockIdx.x * 4 + (threadIdx.x >> 6);
    const int lane = threadIdx.x & 63;
    const int d4 = lane * 4;

    const int beg = offs[node] + bpre[node >> 9];
    const int end = (node + 1 == N_NODES) ? N_EDGES
                                          : (offs[node + 1] + bpre[(node + 1) >> 9]);

    const ushort4 hdv = *(const ushort4*)(h_dst + (size_t)node * 256 + d4);
    const float hd0 = bf2f(hdv.x), hd1 = bf2f(hdv.y), hd2 = bf2f(hdv.z), hd3 = bf2f(hdv.w);
    const float4 araw = *(const float4*)(attn + d4);
    const float av0 = araw.x * LOG2E, av1 = araw.y * LOG2E,
                av2 = araw.z * LOG2E, av3 = araw.w * LOG2E;
    const float aw0 = av0 * SLOPE, aw1 = av1 * SLOPE,
                aw2 = av2 * SLOPE, aw3 = av3 * SLOPE;

    float wsum = 0.f, a0 = 0.f, a1 = 0.f, a2 = 0.f, a3 = 0.f;

    // one edge: returns weight, accumulates
#define EDGE_BODY(sreg)                                                          \
    {                                                                            \
        const unsigned short* row = h_src + (size_t)(sreg) * 256;                \
        const ushort4 va = *(const ushort4*)(row + d4);                          \
        const float r0 = bf2f(va.x), r1 = bf2f(va.y);                            \
        const float r2 = bf2f(va.z), r3 = bf2f(va.w);                            \
        const float y0 = r0 + hd0, y1 = r1 + hd1, y2 = r2 + hd2, y3 = r3 + hd3;  \
        float pp = av0 * fmaxf(y0, 0.f) + aw0 * fminf(y0, 0.f);                  \
        pp = fmaf(av1, fmaxf(y1, 0.f), fmaf(aw1, fminf(y1, 0.f), pp));           \
        pp = fmaf(av2, fmaxf(y2, 0.f), fmaf(aw2, fminf(y2, 0.f), pp));           \
        pp = fmaf(av3, fmaxf(y3, 0.f), fmaf(aw3, fminf(y3, 0.f), pp));           \
        pp = group16_sum(pp);                                                    \
        const float wg = __builtin_amdgcn_exp2f(pp);                             \
        wsum += wg;                                                              \
        a0 = fmaf(wg, r0, a0);                                                   \
        a1 = fmaf(wg, r1, a1);                                                   \
        a2 = fmaf(wg, r2, a2);                                                   \
        a3 = fmaf(wg, r3, a3);                                                   \
    }

    int p = beg;
    const int nfull = (end - beg) >> 2;
    for (int it = 0; it < nfull; ++it, p += 4) {
        const int s0 = __builtin_amdgcn_readfirstlane(srcl[p]);
        const int s1 = __builtin_amdgcn_readfirstlane(srcl[p + 1]);
        const int s2 = __builtin_amdgcn_readfirstlane(srcl[p + 2]);
        const int s3 = __builtin_amdgcn_readfirstlane(srcl[p + 3]);
        EDGE_BODY(s0);
        EDGE_BODY(s1);
        EDGE_BODY(s2);
        EDGE_BODY(s3);
    }
    for (; p < end; ++p) {
        const int s0 = __builtin_amdgcn_readfirstlane(srcl[p]);
        EDGE_BODY(s0);
    }
#undef EDGE_BODY

    const float inv = (wsum > 0.f) ? 1.f / wsum : 0.f;
    const float4 ob = *(const float4*)(out_bias + d4);
    ushort4 o;
    o.x = f2bf(fmaf(a0, inv, ob.x));
    o.y = f2bf(fmaf(a1, inv, ob.y));
    o.z = f2bf(fmaf(a2, inv, ob.z));
    o.w = f2bf(fmaf(a3, inv, ob.w));
    *(ushort4*)(rst + (size_t)node * 256 + d4) = o;
}

// ---------------------------------------------------------------------------
// BatchNorm finalize + LeakyReLU
// ---------------------------------------------------------------------------
__global__ void bn_final_kernel(float* __restrict__ z,
                                const float* __restrict__ sums,
                                const float* __restrict__ gamma,
                                const float* __restrict__ beta) {
    const int i = blockIdx.x * 256 + threadIdx.x;
    if (i < N_NODES * 64) {
        const int col = i & 63;
        const float mu  = sums[col] * (1.f / N_NODES);
        const float var = sums[64 + col] * (1.f / N_NODES) - mu * mu;
        const float v = (z[i] - mu) * rsqrtf(var + BN_EPS) * gamma[col] + beta[col];
        z[i] = leaky(v);
    }
}

// ---------------------------------------------------------------------------
extern "C" void kernel_launch(void* const* d_in, const int* in_sizes, int n_in,
                              void* d_out, int out_size, void* d_ws, size_t ws_size,
                              hipStream_t stream) {
    const float* feat    = (const float*)d_in[0];
    const int*   src     = (const int*)  d_in[1];
    const int*   dst     = (const int*)  d_in[2];
    const float* W_src   = (const float*)d_in[3];
    const float* b_src   = (const float*)d_in[4];
    const float* W_dst   = (const float*)d_in[5];
    const float* b_dst   = (const float*)d_in[6];
    const float* attn    = (const float*)d_in[7];
    const float* out_bias= (const float*)d_in[8];
    const float* fc_W    = (const float*)d_in[9];
    const float* fc_b    = (const float*)d_in[10];
    const float* gamma   = (const float*)d_in[11];
    const float* beta    = (const float*)d_in[12];
    float* z = (float*)d_out;

    char* ws = (char*)d_ws;
    size_t off = 0;
    auto carve = [&](size_t bytes) -> void* {
        void* p = ws + off;
        off = (off + bytes + 255) & ~(size_t)255;
        return p;
    };
    unsigned short* feat_bf = (unsigned short*)carve((size_t)N_NODES * 256 * 2);
    unsigned short* h_src_bf= (unsigned short*)carve((size_t)N_NODES * 256 * 2);
    unsigned short* h_dst_bf= (unsigned short*)carve((size_t)N_NODES * 256 * 2);
    unsigned short* rst_bf  = (unsigned short*)carve((size_t)N_NODES * 256 * 2);
    unsigned short* WtS     = (unsigned short*)carve((size_t)256 * 256 * 2);
    unsigned short* WtD     = (unsigned short*)carve((size_t)256 * 256 * 2);
    unsigned short* WtF     = (unsigned short*)carve((size_t)64 * 256 * 2);
    int*   srcl   = (int*)  carve((size_t)N_EDGES * 4);
    int*   cnt    = (int*)  carve((size_t)2 * N_NODES * 4);
    int*   cursor = cnt + N_NODES;
    int*   offs   = (int*)  carve((size_t)(N_NODES + 1) * 4);
    int*   bsum   = (int*)  carve(128 * 4);
    int*   bpre   = (int*)  carve(128 * 4);
    float* sums   = (float*)carve(128 * 4);
    int*   done   = (int*)  carve(64);

    const int nchunks = (N_NODES + 511) / 512;      // 98

    // prep: cast + transposes + zeroing
    prep_kernel<<<13175, 256, 0, stream>>>(feat, W_src, W_dst, fc_W,
                                           feat_bf, WtS, WtD, WtF, cnt, sums, done);

    // input projections (persistent-B, fragment-ordered LDS)
    proj_kernel<<<dim3(98, 8), 256, 0, stream>>>(
        feat_bf, WtS, WtD, b_src, b_dst, h_src_bf, h_dst_bf);

    // CSR by dst (hist -> merged scan -> scatter)
    hist_kernel<<<(N_EDGES + 255) / 256, 256, 0, stream>>>(dst, cnt);
    scan_kernel<<<nchunks, 512, 0, stream>>>(cnt, offs, bsum, bpre, done);
    scatter_kernel<<<(N_EDGES + 255) / 256, 256, 0, stream>>>(src, dst, offs, bpre, cursor, srcl);

    // fused score + softmax + aggregation (1 wave per node, DPP reductions)
    agg_fused_kernel<<<N_NODES / 4, 256, 0, stream>>>(h_src_bf, h_dst_bf, srcl, offs, bpre,
                                                      attn, out_bias, rst_bf);

    // trailing fc + BN partial stats
    fc_bn_kernel<<<(N_NODES + 63) / 64, 256, 0, stream>>>(rst_bf, WtF, fc_b, z, sums, N_NODES);

    // batchnorm finalize + leaky
    bn_final_kernel<<<(N_NODES * 64 + 255) / 256, 256, 0, stream>>>(z, sums, gamma, beta);
}